// Round 7
// baseline (266.137 us; speedup 1.0000x reference)
//
#include <hip/hip_runtime.h>
#include <math.h>

// x: [28, 256, 128, 128] fp32; group lens {4,3,4,4,3,4,2,4} (starts = prefix).
// Group slab [L,256,16384] viewed [256,L,16384]: cluster c uses slab rows
// c*L..c*L+L-1 (16384 floats each). out[g, c*L+q, :] =
//   sum_k softmax_k(dot(row_q,row_k)/16) * row_k  for c*L+q < 256.
//
// Single kernel, spin-free: block = (cluster, chunk). Each block computes its
// chunk's partial gram, publishes it (agent-scope), atomically bumps the
// cluster counter, and EXITS unless it is the 8th (last) sibling. The last
// sibling ("winner") sums partials -> softmax -> weighted sum for the whole
// cluster, re-reading the 8 chunks while they are still LLC-hot (siblings are
// dispatch-adjacent). HBM: 134 MB read + 134 MB write; re-read hits LLC.

#define DIMD   16384
#define NCH    256
#define NCHUNK 8
#define CHUNKF 2048          // floats per row-chunk
#define CHUNK4 512           // float4 per row-chunk
#define MAXNP  10
#define NCLUST 620
#define PART_STRIDE (NCHUNK * MAXNP)          // 80 floats per cluster
#define CNT_OFF_FLOATS (NCLUST * PART_STRIDE) // 49600

typedef float f32x4 __attribute__((ext_vector_type(4)));

template <int L>
__device__ __forceinline__ void do_cluster(const float* __restrict__ base,
                                           float* __restrict__ outp,
                                           float* __restrict__ part_c,
                                           unsigned int* __restrict__ cnt,
                                           int chunk, int nout, int tid) {
    constexpr int NP = L * (L + 1) / 2;
    __shared__ float red[4][NP];
    __shared__ float S_l[NP];
    __shared__ int win_flag;
    const int lane = tid & 63, wave = tid >> 6;

    // ---- phase 1: partial gram over this chunk ----
    float acc[NP];
    #pragma unroll
    for (int p = 0; p < NP; ++p) acc[p] = 0.f;

    #pragma unroll
    for (int i = 0; i < 2; ++i) {
        const int e4 = chunk * CHUNK4 + i * 256 + tid;
        float4 v[L];
        #pragma unroll
        for (int k = 0; k < L; ++k) v[k] = ((const float4*)(base + (size_t)k * DIMD))[e4];
        int idx = 0;
        #pragma unroll
        for (int a = 0; a < L; ++a) {
            #pragma unroll
            for (int b = a; b < L; ++b) {
                acc[idx] = fmaf(v[a].x, v[b].x, acc[idx]);
                acc[idx] = fmaf(v[a].y, v[b].y, acc[idx]);
                acc[idx] = fmaf(v[a].z, v[b].z, acc[idx]);
                acc[idx] = fmaf(v[a].w, v[b].w, acc[idx]);
                ++idx;
            }
        }
    }

    #pragma unroll
    for (int p = 0; p < NP; ++p) {
        float s = acc[p];
        #pragma unroll
        for (int off = 32; off > 0; off >>= 1) s += __shfl_down(s, off, 64);
        if (lane == 0) red[wave][p] = s;
    }
    __syncthreads();

    // ---- publish partials, bump counter, decide winner ----
    if (tid == 0) {
        #pragma unroll
        for (int p = 0; p < NP; ++p) {
            const float v = red[0][p] + red[1][p] + red[2][p] + red[3][p];
            __hip_atomic_store(&part_c[chunk * MAXNP + p], v,
                               __ATOMIC_RELAXED, __HIP_MEMORY_SCOPE_AGENT);
        }
        const unsigned int old = __hip_atomic_fetch_add(cnt, 1u, __ATOMIC_ACQ_REL,
                                                        __HIP_MEMORY_SCOPE_AGENT);
        win_flag = (old == NCHUNK - 1);
    }
    __syncthreads();
    if (!win_flag) return;

    // ---- winner: final gram + softmax ----
    if (tid < NP) {
        float s = 0.f;
        #pragma unroll
        for (int ch = 0; ch < NCHUNK; ++ch)
            s += __hip_atomic_load(&part_c[ch * MAXNP + tid],
                                   __ATOMIC_RELAXED, __HIP_MEMORY_SCOPE_AGENT);
        S_l[tid] = s * 0.0625f;   // 1/sqrt(256)
    }
    __syncthreads();

    float S[L][L];
    {
        int idx = 0;
        #pragma unroll
        for (int a = 0; a < L; ++a)
            #pragma unroll
            for (int b = a; b < L; ++b) { float s = S_l[idx]; S[a][b] = s; S[b][a] = s; ++idx; }
    }
    float W[L][L];
    #pragma unroll
    for (int q = 0; q < L; ++q) {
        float m = S[q][0];
        #pragma unroll
        for (int k = 1; k < L; ++k) m = fmaxf(m, S[q][k]);
        float den = 0.f;
        #pragma unroll
        for (int k = 0; k < L; ++k) { W[q][k] = expf(S[q][k] - m); den += W[q][k]; }
        const float inv = 1.0f / den;
        #pragma unroll
        for (int k = 0; k < L; ++k) W[q][k] *= inv;
    }

    // ---- winner: weighted sum for ALL 8 chunks (LLC-hot re-read) ----
    #pragma unroll
    for (int ch = 0; ch < NCHUNK; ++ch) {
        #pragma unroll
        for (int i = 0; i < 2; ++i) {
            const int e4 = ch * CHUNK4 + i * 256 + tid;
            float4 v[L];
            #pragma unroll
            for (int k = 0; k < L; ++k) v[k] = ((const float4*)(base + (size_t)k * DIMD))[e4];
            for (int q = 0; q < nout; ++q) {
                float4 o = {0.f, 0.f, 0.f, 0.f};
                #pragma unroll
                for (int k = 0; k < L; ++k) {
                    const float w = W[q][k];
                    o.x = fmaf(w, v[k].x, o.x);
                    o.y = fmaf(w, v[k].y, o.y);
                    o.z = fmaf(w, v[k].z, o.z);
                    o.w = fmaf(w, v[k].w, o.w);
                }
                f32x4 ov = {o.x, o.y, o.z, o.w};
                __builtin_nontemporal_store(ov, (f32x4*)((float4*)(outp + (size_t)q * DIMD) + e4));
            }
        }
    }
}

__global__ __launch_bounds__(256) void attfusion_lastsib(const float* __restrict__ x,
                                                         float* __restrict__ out,
                                                         float* __restrict__ ws) {
    const int lens[8]   = {4, 3, 4, 4, 3, 4, 2, 4};
    const int starts[8] = {0, 4, 7, 11, 15, 18, 22, 24};
    const int coff[9]   = {0, 64, 150, 214, 278, 364, 428, 556, 620};

    const int cluster = blockIdx.x >> 3;
    const int chunk   = blockIdx.x & 7;
    int g = 0;
    while (cluster >= coff[g + 1]) ++g;
    const int c = cluster - coff[g];
    const int L = lens[g];

    const float* base = x + ((size_t)starts[g] * NCH + (size_t)c * L) * DIMD;
    float* outp = out + ((size_t)g * NCH + (size_t)c * L) * DIMD;
    float* part_c = ws + (size_t)cluster * PART_STRIDE;
    unsigned int* cnt = (unsigned int*)(ws + CNT_OFF_FLOATS) + cluster;
    const int nout = min(L, NCH - c * L);
    const int tid = threadIdx.x;

    if (L == 4)      do_cluster<4>(base, outp, part_c, cnt, chunk, nout, tid);
    else if (L == 3) do_cluster<3>(base, outp, part_c, cnt, chunk, nout, tid);
    else             do_cluster<2>(base, outp, part_c, cnt, chunk, nout, tid);
}

extern "C" void kernel_launch(void* const* d_in, const int* in_sizes, int n_in,
                              void* d_out, int out_size, void* d_ws, size_t ws_size,
                              hipStream_t stream) {
    const float* x = (const float*)d_in[0];
    float* out = (float*)d_out;
    float* ws = (float*)d_ws;
    // zero the per-cluster counters (graph-capturable)
    hipMemsetAsync((char*)d_ws + CNT_OFF_FLOATS * sizeof(float), 0,
                   NCLUST * sizeof(unsigned int), stream);
    attfusion_lastsib<<<dim3(NCLUST * NCHUNK), dim3(256), 0, stream>>>(x, out, ws);
}

// Round 8
// 49.884 us; speedup vs baseline: 5.3351x; 5.3351x over previous
//
#include <hip/hip_runtime.h>
#include <math.h>

// x: [28, 256, 128, 128] fp32; group lens {4,3,4,4,3,4,2,4} (starts = prefix).
// Group slab [L,256,16384] viewed [256,L,16384]: cluster c uses slab rows
// c*L..c*L+L-1 (16384 floats each). out[g, c*L+q, :] =
//   sum_k softmax_k(dot(row_q,row_k)/16) * row_k  for c*L+q < 256.
//
// One block (1024 threads) per cluster. The entire cluster (<=256 KB) lives in
// registers: 16 float4/thread for L=4. Gram in-register -> 2-level reduce ->
// redundant per-thread softmax -> weighted sum from registers -> NT store.
// x is read exactly once, out written exactly once; no re-read, no LLC
// dependence, no cross-block sync. Blocks ordered LPT (L=4 first).

#define DIMD 16384
#define NCH  256
#define ROW4 4096   // float4 per row

typedef float f32x4 __attribute__((ext_vector_type(4)));

template <int L>
__device__ __forceinline__ void do_cluster(const float* __restrict__ base,
                                           float* __restrict__ outp,
                                           int nout, int tid) {
    constexpr int NP  = L * (L + 1) / 2;
    constexpr int PER = ROW4 / 1024;      // 4 float4 per row per thread
    __shared__ float red[16][NP];
    __shared__ float S_l[NP];

    const int lane = tid & 63, wave = tid >> 6;

    // ---- load whole cluster into registers (coalesced) ----
    float4 v[L][PER];
    #pragma unroll
    for (int k = 0; k < L; ++k) {
        const float4* row = (const float4*)(base + (size_t)k * DIMD);
        #pragma unroll
        for (int i = 0; i < PER; ++i) v[k][i] = row[i * 1024 + tid];
    }

    // ---- gram partials in-register ----
    float acc[NP];
    #pragma unroll
    for (int p = 0; p < NP; ++p) acc[p] = 0.f;
    #pragma unroll
    for (int i = 0; i < PER; ++i) {
        int idx = 0;
        #pragma unroll
        for (int a = 0; a < L; ++a) {
            #pragma unroll
            for (int b = a; b < L; ++b) {
                acc[idx] = fmaf(v[a][i].x, v[b][i].x, acc[idx]);
                acc[idx] = fmaf(v[a][i].y, v[b][i].y, acc[idx]);
                acc[idx] = fmaf(v[a][i].z, v[b][i].z, acc[idx]);
                acc[idx] = fmaf(v[a][i].w, v[b][i].w, acc[idx]);
                ++idx;
            }
        }
    }

    // ---- reduce: wave shuffle, then 16-wave LDS reduce ----
    #pragma unroll
    for (int p = 0; p < NP; ++p) {
        float s = acc[p];
        #pragma unroll
        for (int off = 32; off > 0; off >>= 1) s += __shfl_down(s, off, 64);
        if (lane == 0) red[wave][p] = s;
    }
    __syncthreads();
    if (tid < NP) {
        float s = 0.f;
        #pragma unroll
        for (int w = 0; w < 16; ++w) s += red[w][tid];
        S_l[tid] = s * 0.0625f;   // 1/sqrt(256)
    }
    __syncthreads();

    // ---- redundant per-thread softmax (tiny) ----
    float S[L][L];
    {
        int idx = 0;
        #pragma unroll
        for (int a = 0; a < L; ++a)
            #pragma unroll
            for (int b = a; b < L; ++b) { const float s = S_l[idx]; S[a][b] = s; S[b][a] = s; ++idx; }
    }
    float W[L][L];
    #pragma unroll
    for (int q = 0; q < L; ++q) {
        float m = S[q][0];
        #pragma unroll
        for (int k = 1; k < L; ++k) m = fmaxf(m, S[q][k]);
        float den = 0.f;
        #pragma unroll
        for (int k = 0; k < L; ++k) { W[q][k] = expf(S[q][k] - m); den += W[q][k]; }
        const float inv = 1.0f / den;
        #pragma unroll
        for (int k = 0; k < L; ++k) W[q][k] *= inv;
    }

    // ---- weighted sum from registers, NT store ----
    for (int q = 0; q < nout; ++q) {
        float* orow = outp + (size_t)q * DIMD;
        #pragma unroll
        for (int i = 0; i < PER; ++i) {
            float4 o = {0.f, 0.f, 0.f, 0.f};
            #pragma unroll
            for (int k = 0; k < L; ++k) {
                const float w = W[q][k];
                o.x = fmaf(w, v[k][i].x, o.x);
                o.y = fmaf(w, v[k][i].y, o.y);
                o.z = fmaf(w, v[k][i].z, o.z);
                o.w = fmaf(w, v[k][i].w, o.w);
            }
            f32x4 ov = {o.x, o.y, o.z, o.w};
            __builtin_nontemporal_store(ov, (f32x4*)((float4*)orow + i * 1024 + tid));
        }
    }
}

__global__ __launch_bounds__(1024, 4) void attfusion_regresident(const float* __restrict__ x,
                                                                 float* __restrict__ out) {
    // LPT block order: 320 L=4 clusters (groups 0,2,3,5,7), then 172 L=3
    // (groups 1,4), then 128 L=2 (group 6).
    const int starts[8] = {0, 4, 7, 11, 15, 18, 22, 24};
    const int g4[5] = {0, 2, 3, 5, 7};
    const int g3[2] = {1, 4};

    const int b = blockIdx.x;
    int g, c, L;
    if (b < 320)      { g = g4[b >> 6];        c = b & 63;          L = 4; }
    else if (b < 492) { g = g3[(b - 320) / 86]; c = (b - 320) % 86; L = 3; }
    else              { g = 6;                  c = b - 492;        L = 2; }

    const float* base = x + ((size_t)starts[g] * NCH + (size_t)c * L) * DIMD;
    float* outp = out + ((size_t)g * NCH + (size_t)c * L) * DIMD;
    const int nout = min(L, NCH - c * L);
    const int tid = threadIdx.x;

    if (L == 4)      do_cluster<4>(base, outp, nout, tid);
    else if (L == 3) do_cluster<3>(base, outp, nout, tid);
    else             do_cluster<2>(base, outp, nout, tid);
}

extern "C" void kernel_launch(void* const* d_in, const int* in_sizes, int n_in,
                              void* d_out, int out_size, void* d_ws, size_t ws_size,
                              hipStream_t stream) {
    const float* x = (const float*)d_in[0];
    float* out = (float*)d_out;
    attfusion_regresident<<<dim3(620), dim3(1024), 0, stream>>>(x, out);
}

// Round 9
// 47.449 us; speedup vs baseline: 5.6089x; 1.0513x over previous
//
#include <hip/hip_runtime.h>
#include <math.h>

// x: [28, 256, 128, 128] fp32; group lens {4,3,4,4,3,4,2,4} (starts = prefix).
// Group slab [L,256,16384] viewed [256,L,16384]: cluster c uses slab rows
// c*L..c*L+L-1 (16384 floats each). out[g, c*L+q, :] =
//   sum_k softmax_k(dot(row_q,row_k)/16) * row_k  for c*L+q < 256.
//
// 257 blocks x 1024 threads; each block runs a STATIC CHAIN of clusters whose
// traffic sums to ~1024 KB: 160x(L4,L4), 86x(L3,L3,L2), 10x(L2 x4), 1x(L2 x2).
// Per cluster: whole cluster in registers (4 float4/row/thread), gram
// in-register -> 2-level reduce -> per-thread softmax -> weighted sum -> NT
// store. Within a chain, cluster i's stores overlap cluster i+1's loads
// (no block-retire barrier), fixing R8's serial 1-block/CU execution.

#define DIMD 16384
#define NCH  256
#define ROW4 4096   // float4 per row

typedef float f32x4 __attribute__((ext_vector_type(4)));

template <int L>
__device__ __forceinline__ void do_cluster(const float* __restrict__ base,
                                           float* __restrict__ outp,
                                           int nout, int tid,
                                           float (*__restrict__ red)[10],
                                           float* __restrict__ S_l) {
    constexpr int NP  = L * (L + 1) / 2;
    constexpr int PER = ROW4 / 1024;      // 4 float4 per row per thread

    const int lane = tid & 63, wave = tid >> 6;

    // ---- load whole cluster into registers (coalesced) ----
    float4 v[L][PER];
    #pragma unroll
    for (int k = 0; k < L; ++k) {
        const float4* row = (const float4*)(base + (size_t)k * DIMD);
        #pragma unroll
        for (int i = 0; i < PER; ++i) v[k][i] = row[i * 1024 + tid];
    }

    // ---- gram partials in-register ----
    float acc[NP];
    #pragma unroll
    for (int p = 0; p < NP; ++p) acc[p] = 0.f;
    #pragma unroll
    for (int i = 0; i < PER; ++i) {
        int idx = 0;
        #pragma unroll
        for (int a = 0; a < L; ++a) {
            #pragma unroll
            for (int b = a; b < L; ++b) {
                acc[idx] = fmaf(v[a][i].x, v[b][i].x, acc[idx]);
                acc[idx] = fmaf(v[a][i].y, v[b][i].y, acc[idx]);
                acc[idx] = fmaf(v[a][i].z, v[b][i].z, acc[idx]);
                acc[idx] = fmaf(v[a][i].w, v[b][i].w, acc[idx]);
                ++idx;
            }
        }
    }

    // ---- reduce: wave shuffle, then 16-wave LDS reduce ----
    #pragma unroll
    for (int p = 0; p < NP; ++p) {
        float s = acc[p];
        #pragma unroll
        for (int off = 32; off > 0; off >>= 1) s += __shfl_down(s, off, 64);
        if (lane == 0) red[wave][p] = s;
    }
    __syncthreads();
    if (tid < NP) {
        float s = 0.f;
        #pragma unroll
        for (int w = 0; w < 16; ++w) s += red[w][tid];
        S_l[tid] = s * 0.0625f;   // 1/sqrt(256)
    }
    __syncthreads();

    // ---- redundant per-thread softmax (tiny) ----
    float S[L][L];
    {
        int idx = 0;
        #pragma unroll
        for (int a = 0; a < L; ++a)
            #pragma unroll
            for (int b = a; b < L; ++b) { const float s = S_l[idx]; S[a][b] = s; S[b][a] = s; ++idx; }
    }
    float W[L][L];
    #pragma unroll
    for (int q = 0; q < L; ++q) {
        float m = S[q][0];
        #pragma unroll
        for (int k = 1; k < L; ++k) m = fmaxf(m, S[q][k]);
        float den = 0.f;
        #pragma unroll
        for (int k = 0; k < L; ++k) { W[q][k] = expf(S[q][k] - m); den += W[q][k]; }
        const float inv = 1.0f / den;
        #pragma unroll
        for (int k = 0; k < L; ++k) W[q][k] *= inv;
    }

    // ---- weighted sum from registers, NT store ----
    for (int q = 0; q < nout; ++q) {
        float* orow = outp + (size_t)q * DIMD;
        #pragma unroll
        for (int i = 0; i < PER; ++i) {
            float4 o = {0.f, 0.f, 0.f, 0.f};
            #pragma unroll
            for (int k = 0; k < L; ++k) {
                const float w = W[q][k];
                o.x = fmaf(w, v[k][i].x, o.x);
                o.y = fmaf(w, v[k][i].y, o.y);
                o.z = fmaf(w, v[k][i].z, o.z);
                o.w = fmaf(w, v[k][i].w, o.w);
            }
            f32x4 ov = {o.x, o.y, o.z, o.w};
            __builtin_nontemporal_store(ov, (f32x4*)((float4*)orow + i * 1024 + tid));
        }
    }
}

// slot s of block b -> (g, c, L); returns false if no cluster in this slot.
__device__ __forceinline__ bool chain_slot(int b, int s, int& g, int& c, int& L) {
    const int g4[5] = {0, 2, 3, 5, 7};
    if (b < 160) {                       // (L4, L4)
        if (s >= 2) return false;
        const int i = b * 2 + s;         // 0..319
        g = g4[i >> 6]; c = i & 63; L = 4;
        return true;
    }
    if (b < 246) {                       // (L3, L3, L2)
        const int j = b - 160;           // 0..85
        if (s < 2) {
            const int i = j * 2 + s;     // 0..171
            g = (i < 86) ? 1 : 4; c = (i < 86) ? i : i - 86; L = 3;
            return true;
        }
        if (s == 2) { g = 6; c = j; L = 2; return true; }
        return false;
    }
    if (b < 256) {                       // (L2 x4)
        const int j = b - 246;           // 0..9
        if (s >= 4) return false;
        g = 6; c = 86 + j * 4 + s; L = 2;
        return true;
    }
    // b == 256: (L2 x2)
    if (s >= 2) return false;
    g = 6; c = 126 + s; L = 2;
    return true;
}

__global__ __launch_bounds__(1024, 4) void attfusion_chain(const float* __restrict__ x,
                                                           float* __restrict__ out) {
    __shared__ float red[16][10];
    __shared__ float S_l[10];
    const int starts[8] = {0, 4, 7, 11, 15, 18, 22, 24};
    const int b = blockIdx.x;
    const int tid = threadIdx.x;

    #pragma unroll 1
    for (int s = 0; s < 4; ++s) {
        int g, c, L;
        if (!chain_slot(b, s, g, c, L)) break;
        const float* base = x + ((size_t)starts[g] * NCH + (size_t)c * L) * DIMD;
        float* outp = out + ((size_t)g * NCH + (size_t)c * L) * DIMD;
        const int nout = min(L, NCH - c * L);
        if (L == 4)      do_cluster<4>(base, outp, nout, tid, red, S_l);
        else if (L == 3) do_cluster<3>(base, outp, nout, tid, red, S_l);
        else             do_cluster<2>(base, outp, nout, tid, red, S_l);
    }
}

extern "C" void kernel_launch(void* const* d_in, const int* in_sizes, int n_in,
                              void* d_out, int out_size, void* d_ws, size_t ws_size,
                              hipStream_t stream) {
    const float* x = (const float*)d_in[0];
    float* out = (float*)d_out;
    attfusion_chain<<<dim3(257), dim3(1024), 0, stream>>>(x, out);
}